// Round 5
// baseline (305.924 us; speedup 1.0000x reference)
//
#include <hip/hip_runtime.h>

#define N_USER 100000
#define N_ITEM 100000
#define NEDGE  500000
#define DEGCAP 32

typedef __attribute__((ext_vector_type(8))) short short8;
typedef __attribute__((ext_vector_type(4))) float f32x4;

__device__ __forceinline__ unsigned short f2bf(float f) {
  union { float f; unsigned int u; } x{f};
  unsigned int r = x.u + 0x7fffu + ((x.u >> 16) & 1u);  // RTN-even
  return (unsigned short)(r >> 16);
}
__device__ __forceinline__ float bf2f(unsigned short u) {
  union { unsigned int u; float f; } x{(unsigned int)u << 16};
  return x.f;
}

// ---------------------------------------------------------------------------
// setup_k (grid-split): [0,3908) padded-CSR fill for both graphs
// (cur pre-zeroed; csr[d*32+p]=src, p from atomic cursor; p>=32 impossible
// statistically, write guarded); [3908,4292) bf16 transposed weight prep:
// WT[N][256] with k<128 from W0, k>=128 from We.
// ---------------------------------------------------------------------------
__global__ __launch_bounds__(256) void setup_k(
    const int* __restrict__ src_ui, const int* __restrict__ dst_ui,
    int* __restrict__ cur_i, int* __restrict__ csr_ui,
    const int* __restrict__ src_iu, const int* __restrict__ dst_iu,
    int* __restrict__ cur_u, int* __restrict__ csr_iu,
    const float* __restrict__ W10, const float* __restrict__ W1ui,
    const float* __restrict__ W1iu, const float* __restrict__ W20,
    const float* __restrict__ W2ui, const float* __restrict__ W2iu,
    unsigned short* __restrict__ WT1i, unsigned short* __restrict__ WT1u,
    unsigned short* __restrict__ WT2i, unsigned short* __restrict__ WT2u) {
  int b = blockIdx.x, tid = threadIdx.x;
  if (b < 3908) {
    const int *src, *dst; int *cur, *csr;
    int bb = b;
    if (bb < 1954) { src = src_ui; dst = dst_ui; cur = cur_i; csr = csr_ui; }
    else { bb -= 1954; src = src_iu; dst = dst_iu; cur = cur_u; csr = csr_iu; }
    int e = bb * 256 + tid;
    if (e < NEDGE) {
      int d = dst[e];
      int p = atomicAdd(&cur[d], 1);
      if (p < DEGCAP) csr[d * DEGCAP + p] = src[e];
    }
  } else {
    int t = (b - 3908) * 256 + tid;  // 0..98303
    if (t < 32768) {
      int n = t >> 8, k = t & 255;
      float v = (k < 128) ? W10[k * 128 + n] : W1ui[(k - 128) * 128 + n];
      WT1i[t] = f2bf(v);
    } else if (t < 65536) {
      int q = t - 32768; int n = q >> 8, k = q & 255;
      float v = (k < 128) ? W10[k * 128 + n] : W1iu[(k - 128) * 128 + n];
      WT1u[q] = f2bf(v);
    } else if (t < 81920) {
      int q = t - 65536; int n = q >> 8, k = q & 255;
      float v = (k < 128) ? W20[k * 64 + n] : W2ui[(k - 128) * 64 + n];
      WT2i[q] = f2bf(v);
    } else {
      int q = t - 81920; int n = q >> 8, k = q & 255;
      float v = (k < 128) ? W20[k * 64 + n] : W2iu[(k - 128) * 64 + n];
      WT2u[q] = f2bf(v);
    }
  }
}

// ---------------------------------------------------------------------------
// Fused gather-mean + double-GEMM (bf16 MFMA, fp32 accum), both ntypes per
// dispatch:  out = A1@W[0:128] + mean_nbr(GF)@W[128:256] + b0 + (deg>0)*be
// kh=0 stages A1 (self rows, coalesced); kh=1 stages the gathered mean tile
// computed on the fly from GF rows via padded CSR. LDS XOR-swizzled.
// GF32: A1/GF are fp32 (layer 1); else bf16 (layer 2).
// ---------------------------------------------------------------------------
template <int N, bool GF32, bool LRELU, bool OUTBF16>
__global__ __launch_bounds__(256) void gemmagg_k(
    const void* __restrict__ A1a, const void* __restrict__ GFa,
    const int* __restrict__ cura, const int* __restrict__ csra,
    const unsigned short* __restrict__ WTa, const float* __restrict__ b0a,
    const float* __restrict__ bea, void* __restrict__ outa,
    const void* __restrict__ A1b, const void* __restrict__ GFb,
    const int* __restrict__ curb, const int* __restrict__ csrb,
    const unsigned short* __restrict__ WTb, const float* __restrict__ b0b,
    const float* __restrict__ beb, void* __restrict__ outb,
    int M, int nbA) {
  constexpr int BM = 64;
  constexpr int CPW = N / 4;
  constexpr int NCF = CPW / 16;
  __shared__ short As[BM * 128];
  __shared__ short Ws[N * 128];
  __shared__ float degmask[BM];

  int blk = blockIdx.x;
  const void* A1v; const void* GFv; const int* cur; const int* csr;
  const unsigned short* WT; const float* b0; const float* be; void* outv;
  if (blk < nbA) { A1v = A1a; GFv = GFa; cur = cura; csr = csra; WT = WTa; b0 = b0a; be = bea; outv = outa; }
  else { blk -= nbA; A1v = A1b; GFv = GFb; cur = curb; csr = csrb; WT = WTb; b0 = b0b; be = beb; outv = outb; }

  const int tid = threadIdx.x;
  const int lane = tid & 63;
  const int wave = tid >> 6;
  const int row0 = blk * BM;
  const int colbase = wave * CPW;

  if (tid < BM) {
    int r = row0 + tid;
    degmask[tid] = (r < M && cur[r] > 0) ? 1.f : 0.f;
  }

  f32x4 acc[4][NCF] = {};

#pragma unroll
  for (int kh = 0; kh < 2; ++kh) {
    __syncthreads();  // also covers degmask before first read
    if (kh == 0) {
      // ---- stage A1 self rows: 64 x 128 bf16 (1024 16B chunks) ----
#pragma unroll
      for (int it = 0; it < 4; ++it) {
        int chunk = tid + it * 256;
        int row = chunk >> 4, c16 = chunk & 15;
        int gr = row0 + row; if (gr > M - 1) gr = M - 1;
        short8 v;
        if (GF32) {
          const float* s = (const float*)A1v + (size_t)gr * 128 + c16 * 8;
          float4 x = *(const float4*)s;
          float4 y = *(const float4*)(s + 4);
          v = short8{(short)f2bf(x.x), (short)f2bf(x.y), (short)f2bf(x.z), (short)f2bf(x.w),
                     (short)f2bf(y.x), (short)f2bf(y.y), (short)f2bf(y.z), (short)f2bf(y.w)};
        } else {
          v = *(const short8*)((const unsigned short*)A1v + (size_t)gr * 128 + c16 * 8);
        }
        int byteoff = row * 256 + ((c16 * 16) ^ ((row & 7) << 4));
        *(short8*)((char*)As + byteoff) = v;
      }
    } else if (GF32) {
      // ---- gather-mean (fp32 rows): 8 groups x 32 lanes, 8 rows/group ----
      int g = tid >> 5, ln = tid & 31;
      const float* gf = (const float*)GFv;
#pragma unroll 2
      for (int rr = 0; rr < 8; ++rr) {
        int row = g * 8 + rr;
        int r = row0 + row;
        int deg = (r < M) ? min(cur[r], DEGCAP) : 0;
        const int* cp = csr + (size_t)r * DEGCAP;
        float4 a = {0.f, 0.f, 0.f, 0.f};
        int j = 0;
        for (; j + 4 <= deg; j += 4) {
          int i0 = cp[j], i1 = cp[j + 1], i2 = cp[j + 2], i3 = cp[j + 3];
          float4 v0 = *(const float4*)(gf + (size_t)i0 * 128 + ln * 4);
          float4 v1 = *(const float4*)(gf + (size_t)i1 * 128 + ln * 4);
          float4 v2 = *(const float4*)(gf + (size_t)i2 * 128 + ln * 4);
          float4 v3 = *(const float4*)(gf + (size_t)i3 * 128 + ln * 4);
          a.x += (v0.x + v1.x) + (v2.x + v3.x);
          a.y += (v0.y + v1.y) + (v2.y + v3.y);
          a.z += (v0.z + v1.z) + (v2.z + v3.z);
          a.w += (v0.w + v1.w) + (v2.w + v3.w);
        }
        for (; j < deg; ++j) {
          float4 v = *(const float4*)(gf + (size_t)cp[j] * 128 + ln * 4);
          a.x += v.x; a.y += v.y; a.z += v.z; a.w += v.w;
        }
        float sc = deg ? 1.f / (float)deg : 0.f;
        unsigned int p0 = ((unsigned int)f2bf(a.y * sc) << 16) | f2bf(a.x * sc);
        unsigned int p1 = ((unsigned int)f2bf(a.w * sc) << 16) | f2bf(a.z * sc);
        int byteoff = row * 256 + ((ln * 8) ^ ((row & 7) << 4));
        *(uint2*)((char*)As + byteoff) = uint2{p0, p1};
      }
    } else {
      // ---- gather-mean (bf16 rows): 16 groups x 16 lanes, 4 rows/group ----
      int g = tid >> 4, ln = tid & 15;
      const unsigned short* gf = (const unsigned short*)GFv;
#pragma unroll 2
      for (int rr = 0; rr < 4; ++rr) {
        int row = g * 4 + rr;
        int r = row0 + row;
        int deg = (r < M) ? min(cur[r], DEGCAP) : 0;
        const int* cp = csr + (size_t)r * DEGCAP;
        float a[8] = {0, 0, 0, 0, 0, 0, 0, 0};
        int j = 0;
        for (; j + 4 <= deg; j += 4) {
          int i0 = cp[j], i1 = cp[j + 1], i2 = cp[j + 2], i3 = cp[j + 3];
          short8 v0 = *(const short8*)(gf + (size_t)i0 * 128 + ln * 8);
          short8 v1 = *(const short8*)(gf + (size_t)i1 * 128 + ln * 8);
          short8 v2 = *(const short8*)(gf + (size_t)i2 * 128 + ln * 8);
          short8 v3 = *(const short8*)(gf + (size_t)i3 * 128 + ln * 8);
#pragma unroll
          for (int d = 0; d < 8; ++d)
            a[d] += (bf2f((unsigned short)v0[d]) + bf2f((unsigned short)v1[d])) +
                    (bf2f((unsigned short)v2[d]) + bf2f((unsigned short)v3[d]));
        }
        for (; j < deg; ++j) {
          short8 v = *(const short8*)(gf + (size_t)cp[j] * 128 + ln * 8);
#pragma unroll
          for (int d = 0; d < 8; ++d) a[d] += bf2f((unsigned short)v[d]);
        }
        float sc = deg ? 1.f / (float)deg : 0.f;
        short8 pk;
#pragma unroll
        for (int d = 0; d < 8; ++d) pk[d] = (short)f2bf(a[d] * sc);
        int byteoff = row * 256 + ((ln * 16) ^ ((row & 7) << 4));
        *(short8*)((char*)As + byteoff) = pk;
      }
    }
    // ---- stage W half kh: N rows x 128 bf16 ----
#pragma unroll
    for (int it = 0; it < (N * 16) / 256; ++it) {
      int chunk = tid + it * 256;
      int n = chunk >> 4, c16 = chunk & 15;
      short8 v = *(const short8*)(WT + (size_t)n * 256 + kh * 128 + c16 * 8);
      int byteoff = n * 256 + ((c16 * 16) ^ ((n & 7) << 4));
      *(short8*)((char*)Ws + byteoff) = v;
    }
    __syncthreads();

#pragma unroll
    for (int ks = 0; ks < 4; ++ks) {
      short8 af[4];
#pragma unroll
      for (int rf = 0; rf < 4; ++rf) {
        int row = rf * 16 + (lane & 15);
        int c16 = ks * 4 + (lane >> 4);
        int byteoff = row * 256 + ((c16 * 16) ^ ((row & 7) << 4));
        af[rf] = *(const short8*)((const char*)As + byteoff);
      }
      short8 wf[NCF];
#pragma unroll
      for (int cf = 0; cf < NCF; ++cf) {
        int n = colbase + cf * 16 + (lane & 15);
        int c16 = ks * 4 + (lane >> 4);
        int byteoff = n * 256 + ((c16 * 16) ^ ((n & 7) << 4));
        wf[cf] = *(const short8*)((const char*)Ws + byteoff);
      }
#pragma unroll
      for (int rf = 0; rf < 4; ++rf)
#pragma unroll
        for (int cf = 0; cf < NCF; ++cf)
          acc[rf][cf] = __builtin_amdgcn_mfma_f32_16x16x32_bf16(
              af[rf], wf[cf], acc[rf][cf], 0, 0, 0);
    }
  }

  // C/D layout: col=lane&15, row=(lane>>4)*4+j  [m89 verified]
#pragma unroll
  for (int cf = 0; cf < NCF; ++cf) {
    int c = colbase + cf * 16 + (lane & 15);
    float bb0 = b0[c], bbe = be[c];
#pragma unroll
    for (int rf = 0; rf < 4; ++rf) {
#pragma unroll
      for (int j = 0; j < 4; ++j) {
        int lr = rf * 16 + (lane >> 4) * 4 + j;
        int r = row0 + lr;
        if (r < M) {
          float v = acc[rf][cf][j] + bb0 + degmask[lr] * bbe;
          if (LRELU) v = (v >= 0.f) ? v : 0.01f * v;
          if (OUTBF16)
            ((unsigned short*)outv)[(size_t)r * N + c] = f2bf(v);
          else
            ((float*)outv)[(size_t)r * N + c] = v;
        }
      }
    }
  }
}

extern "C" void kernel_launch(void* const* d_in, const int* in_sizes, int n_in,
                              void* d_out, int out_size, void* d_ws,
                              size_t ws_size, hipStream_t stream) {
  const float* emb_u = (const float*)d_in[0];
  const float* emb_i = (const float*)d_in[1];
  const float* W1_0  = (const float*)d_in[2];
  const float* b1_0  = (const float*)d_in[3];
  const float* W1_ui = (const float*)d_in[4];
  const float* b1_ui = (const float*)d_in[5];
  const float* W1_iu = (const float*)d_in[6];
  const float* b1_iu = (const float*)d_in[7];
  const float* W2_0  = (const float*)d_in[8];
  const float* b2_0  = (const float*)d_in[9];
  const float* W2_ui = (const float*)d_in[10];
  const float* b2_ui = (const float*)d_in[11];
  const float* W2_iu = (const float*)d_in[12];
  const float* b2_iu = (const float*)d_in[13];
  const int* src_ui = (const int*)d_in[14];
  const int* dst_ui = (const int*)d_in[15];
  const int* src_iu = (const int*)d_in[16];
  const int* dst_iu = (const int*)d_in[17];
  float* out = (float*)d_out;

  // ---- workspace layout (~78 MB) ----
  char* p = (char*)d_ws;
  unsigned short* WT1i = (unsigned short*)p; p += 65536;
  unsigned short* WT1u = (unsigned short*)p; p += 65536;
  unsigned short* WT2i = (unsigned short*)p; p += 32768;
  unsigned short* WT2u = (unsigned short*)p; p += 32768;
  int* cur_i = (int*)p; p += 400128;                 // degrees (item side)
  int* cur_u = (int*)p; p += 400128;                 // degrees (user side)
  int* csr_ui = (int*)p; p += (size_t)100032 * DEGCAP * 4;  // 12.8 MB
  int* csr_iu = (int*)p; p += (size_t)100032 * DEGCAP * 4;
  const size_t FB = (size_t)N_USER * 128 * 2;        // 25.6 MB
  unsigned short* hu = (unsigned short*)p; p += FB;
  unsigned short* hi = (unsigned short*)p; p += FB;

  const int GG = (N_USER + 63) / 64;  // 1563

  hipMemsetAsync(cur_i, 0, 2 * 400128, stream);
  setup_k<<<4292, 256, 0, stream>>>(src_ui, dst_ui, cur_i, csr_ui,
                                    src_iu, dst_iu, cur_u, csr_iu,
                                    W1_0, W1_ui, W1_iu, W2_0, W2_ui, W2_iu,
                                    WT1i, WT1u, WT2i, WT2u);

  // layer 1: h_i = lrelu(emb_i@W0 + mean_ui(emb_u)@Wui + b), h_u likewise
  gemmagg_k<128, true, true, true><<<2 * GG, 256, 0, stream>>>(
      emb_i, emb_u, cur_i, csr_ui, WT1i, b1_0, b1_ui, hi,
      emb_u, emb_i, cur_u, csr_iu, WT1u, b1_0, b1_iu, hu, N_USER, GG);

  // layer 2: out_i = hi@W0 + mean_ui(hu)@Wui + b -> d_out 2nd half; out_u 1st
  gemmagg_k<64, false, false, false><<<2 * GG, 256, 0, stream>>>(
      hi, hu, cur_i, csr_ui, WT2i, b2_0, b2_ui, out + (size_t)N_USER * 64,
      hu, hi, cur_u, csr_iu, WT2u, b2_0, b2_iu, out, N_USER, GG);
}

// Round 6
// 253.721 us; speedup vs baseline: 1.2058x; 1.2058x over previous
//
#include <hip/hip_runtime.h>

#define N_USER 100000
#define N_ITEM 100000
#define NEDGE  500000
#define DEGCAP 32

typedef __attribute__((ext_vector_type(8))) short short8;
typedef __attribute__((ext_vector_type(4))) float f32x4;

__device__ __forceinline__ unsigned short f2bf(float f) {
  union { float f; unsigned int u; } x{f};
  unsigned int r = x.u + 0x7fffu + ((x.u >> 16) & 1u);  // RTN-even
  return (unsigned short)(r >> 16);
}
__device__ __forceinline__ float bf2f(unsigned short u) {
  union { unsigned int u; float f; } x{(unsigned int)u << 16};
  return x.f;
}

// ---------------------------------------------------------------------------
// setup_k (grid-split):
//  [0,3908)      padded-CSR fill, both graphs (cur pre-zeroed by memset;
//                csr[d*32 + atomic-cursor] = src; deg>32 impossible at
//                Poisson(5), write guarded anyway)
//  [3908,16408)  emb fp32 -> bf16 conversion (both ntypes)
//  [16408,16792) transposed bf16 weight prep: WT[N][256], k<128 from W0,
//                k>=128 from We
// ---------------------------------------------------------------------------
__global__ __launch_bounds__(256) void setup_k(
    const int* __restrict__ src_ui, const int* __restrict__ dst_ui,
    int* __restrict__ cur_i, int* __restrict__ csr_ui,
    const int* __restrict__ src_iu, const int* __restrict__ dst_iu,
    int* __restrict__ cur_u, int* __restrict__ csr_iu,
    const float* __restrict__ emb_u, const float* __restrict__ emb_i,
    unsigned short* __restrict__ ebu, unsigned short* __restrict__ ebi,
    const float* __restrict__ W10, const float* __restrict__ W1ui,
    const float* __restrict__ W1iu, const float* __restrict__ W20,
    const float* __restrict__ W2ui, const float* __restrict__ W2iu,
    unsigned short* __restrict__ WT1i, unsigned short* __restrict__ WT1u,
    unsigned short* __restrict__ WT2i, unsigned short* __restrict__ WT2u) {
  int b = blockIdx.x, tid = threadIdx.x;
  if (b < 3908) {
    const int *src, *dst; int *cur, *csr;
    int bb = b;
    if (bb < 1954) { src = src_ui; dst = dst_ui; cur = cur_i; csr = csr_ui; }
    else { bb -= 1954; src = src_iu; dst = dst_iu; cur = cur_u; csr = csr_iu; }
    int e = bb * 256 + tid;
    if (e < NEDGE) {
      int d = dst[e];
      int p = atomicAdd(&cur[d], 1);
      if (p < DEGCAP) csr[d * DEGCAP + p] = src[e];
    }
  } else if (b < 16408) {
    int blk = b - 3908;
    const float* src; unsigned short* dstp;
    if (blk < 6250) { src = emb_u; dstp = ebu; }
    else { blk -= 6250; src = emb_i; dstp = ebi; }
    size_t base = (size_t)blk * 2048 + (size_t)tid * 8;
    float4 x = *(const float4*)(src + base);
    float4 y = *(const float4*)(src + base + 4);
    short8 v{(short)f2bf(x.x), (short)f2bf(x.y), (short)f2bf(x.z), (short)f2bf(x.w),
             (short)f2bf(y.x), (short)f2bf(y.y), (short)f2bf(y.z), (short)f2bf(y.w)};
    *(short8*)(dstp + base) = v;
  } else {
    int t = (b - 16408) * 256 + tid;  // 0..98303
    if (t < 32768) {
      int n = t >> 8, k = t & 255;
      float v = (k < 128) ? W10[k * 128 + n] : W1ui[(k - 128) * 128 + n];
      WT1i[t] = f2bf(v);
    } else if (t < 65536) {
      int q = t - 32768; int n = q >> 8, k = q & 255;
      float v = (k < 128) ? W10[k * 128 + n] : W1iu[(k - 128) * 128 + n];
      WT1u[q] = f2bf(v);
    } else if (t < 81920) {
      int q = t - 65536; int n = q >> 8, k = q & 255;
      float v = (k < 128) ? W20[k * 64 + n] : W2ui[(k - 128) * 64 + n];
      WT2i[q] = f2bf(v);
    } else {
      int q = t - 81920; int n = q >> 8, k = q & 255;
      float v = (k < 128) ? W20[k * 64 + n] : W2iu[(k - 128) * 64 + n];
      WT2u[q] = f2bf(v);
    }
  }
}

// ---------------------------------------------------------------------------
// Gather-mean aggregation (bf16 src, 128-dim), both directions per dispatch.
// Padded CSR (stride 32, degree in cur). 16 lanes/node (short8/lane),
// 16 nodes/block. Edge loop unrolled x4 with next-group index prefetch.
// High-occupancy (no LDS, few VGPRs) — keep latency-bound gather separate
// from the LDS-capped GEMM (R5 fusion regression).
// ---------------------------------------------------------------------------
__global__ __launch_bounds__(256) void agg2_k(
    const unsigned short* __restrict__ featA, const int* __restrict__ curA,
    const int* __restrict__ csrA, unsigned short* __restrict__ outA,
    const unsigned short* __restrict__ featB, const int* __restrict__ curB,
    const int* __restrict__ csrB, unsigned short* __restrict__ outB,
    int nbA) {
  int b = blockIdx.x;
  const unsigned short* feat; const int* cur; const int* csr; unsigned short* out;
  if (b < nbA) { feat = featA; cur = curA; csr = csrA; out = outA; }
  else { b -= nbA; feat = featB; cur = curB; csr = csrB; out = outB; }
  int node = b * 16 + (threadIdx.x >> 4);
  int ln = threadIdx.x & 15;
  int deg = min(cur[node], DEGCAP);
  const int* cp = csr + (size_t)node * DEGCAP;
  float a[8] = {0, 0, 0, 0, 0, 0, 0, 0};
  int j = 0;
  if (j + 4 <= deg) {
    int i0 = cp[0], i1 = cp[1], i2 = cp[2], i3 = cp[3];
    for (;;) {
      bool more = (j + 8 <= deg);
      int n0, n1, n2, n3;
      if (more) { n0 = cp[j + 4]; n1 = cp[j + 5]; n2 = cp[j + 6]; n3 = cp[j + 7]; }
      short8 v0 = *(const short8*)(feat + (size_t)i0 * 128 + ln * 8);
      short8 v1 = *(const short8*)(feat + (size_t)i1 * 128 + ln * 8);
      short8 v2 = *(const short8*)(feat + (size_t)i2 * 128 + ln * 8);
      short8 v3 = *(const short8*)(feat + (size_t)i3 * 128 + ln * 8);
#pragma unroll
      for (int d = 0; d < 8; ++d)
        a[d] += (bf2f((unsigned short)v0[d]) + bf2f((unsigned short)v1[d])) +
                (bf2f((unsigned short)v2[d]) + bf2f((unsigned short)v3[d]));
      j += 4;
      if (!more) break;
      i0 = n0; i1 = n1; i2 = n2; i3 = n3;
    }
  }
  if (j + 2 <= deg) {
    int i0 = cp[j], i1 = cp[j + 1];
    short8 v0 = *(const short8*)(feat + (size_t)i0 * 128 + ln * 8);
    short8 v1 = *(const short8*)(feat + (size_t)i1 * 128 + ln * 8);
#pragma unroll
    for (int d = 0; d < 8; ++d)
      a[d] += bf2f((unsigned short)v0[d]) + bf2f((unsigned short)v1[d]);
    j += 2;
  }
  if (j < deg) {
    short8 v = *(const short8*)(feat + (size_t)cp[j] * 128 + ln * 8);
#pragma unroll
    for (int d = 0; d < 8; ++d) a[d] += bf2f((unsigned short)v[d]);
  }
  float sc = deg ? 1.f / (float)deg : 0.f;
  short8 pk;
#pragma unroll
  for (int d = 0; d < 8; ++d) pk[d] = (short)f2bf(a[d] * sc);
  *(short8*)(out + (size_t)node * 128 + ln * 8) = pk;
}

// ---------------------------------------------------------------------------
// Fused double-GEMM (bf16 MFMA, fp32 accum), both ntypes per dispatch:
//   out = A1@W[0:128] + A2@W[128:256] + b0 + (deg>0)*be  [, lrelu]
// A1, A2: [M][128] bf16. WT: [N][256] bf16 pre-transposed.
// BM=64, 4 waves, wave w owns cols [w*N/4,(w+1)*N/4). LDS XOR-swizzled.
// In-place out==A1 safe: block reads only its own rows, stage precedes write.
// ---------------------------------------------------------------------------
template <int N, bool LRELU, bool OUTBF16>
__global__ __launch_bounds__(256) void gemm2_k(
    const unsigned short* __restrict__ A1a, const unsigned short* __restrict__ A2a,
    const unsigned short* __restrict__ WTa, const float* __restrict__ b0a,
    const float* __restrict__ bea, const int* __restrict__ cura,
    void* __restrict__ outa,
    const unsigned short* __restrict__ A1b, const unsigned short* __restrict__ A2b,
    const unsigned short* __restrict__ WTb, const float* __restrict__ b0b,
    const float* __restrict__ beb, const int* __restrict__ curb,
    void* __restrict__ outb, int M, int nbA) {
  constexpr int BM = 64;
  constexpr int CPW = N / 4;
  constexpr int NCF = CPW / 16;
  __shared__ short As[BM * 128];
  __shared__ short Ws[N * 128];
  __shared__ float degmask[BM];

  int blk = blockIdx.x;
  const unsigned short* A1; const unsigned short* A2; const unsigned short* WT;
  const float* b0; const float* be; const int* cur; void* outv;
  if (blk < nbA) { A1 = A1a; A2 = A2a; WT = WTa; b0 = b0a; be = bea; cur = cura; outv = outa; }
  else { blk -= nbA; A1 = A1b; A2 = A2b; WT = WTb; b0 = b0b; be = beb; cur = curb; outv = outb; }

  const int tid = threadIdx.x;
  const int lane = tid & 63;
  const int wave = tid >> 6;
  const int row0 = blk * BM;
  const int colbase = wave * CPW;

  if (tid < BM) {
    int r = row0 + tid;
    degmask[tid] = (r < M && cur[r] > 0) ? 1.f : 0.f;
  }

  f32x4 acc[4][NCF] = {};

#pragma unroll
  for (int kh = 0; kh < 2; ++kh) {
    __syncthreads();
    const unsigned short* base = (kh == 0) ? A1 : A2;
#pragma unroll
    for (int it = 0; it < 4; ++it) {
      int chunk = tid + it * 256;
      int row = chunk >> 4, c16 = chunk & 15;
      int gr = row0 + row; if (gr > M - 1) gr = M - 1;
      short8 v = *(const short8*)(base + (size_t)gr * 128 + c16 * 8);
      int byteoff = row * 256 + ((c16 * 16) ^ ((row & 7) << 4));
      *(short8*)((char*)As + byteoff) = v;
    }
#pragma unroll
    for (int it = 0; it < (N * 16) / 256; ++it) {
      int chunk = tid + it * 256;
      int n = chunk >> 4, c16 = chunk & 15;
      short8 v = *(const short8*)(WT + (size_t)n * 256 + kh * 128 + c16 * 8);
      int byteoff = n * 256 + ((c16 * 16) ^ ((n & 7) << 4));
      *(short8*)((char*)Ws + byteoff) = v;
    }
    __syncthreads();

#pragma unroll
    for (int ks = 0; ks < 4; ++ks) {
      short8 af[4];
#pragma unroll
      for (int rf = 0; rf < 4; ++rf) {
        int row = rf * 16 + (lane & 15);
        int c16 = ks * 4 + (lane >> 4);
        int byteoff = row * 256 + ((c16 * 16) ^ ((row & 7) << 4));
        af[rf] = *(const short8*)((const char*)As + byteoff);
      }
      short8 wf[NCF];
#pragma unroll
      for (int cf = 0; cf < NCF; ++cf) {
        int n = colbase + cf * 16 + (lane & 15);
        int c16 = ks * 4 + (lane >> 4);
        int byteoff = n * 256 + ((c16 * 16) ^ ((n & 7) << 4));
        wf[cf] = *(const short8*)((const char*)Ws + byteoff);
      }
#pragma unroll
      for (int rf = 0; rf < 4; ++rf)
#pragma unroll
        for (int cf = 0; cf < NCF; ++cf)
          acc[rf][cf] = __builtin_amdgcn_mfma_f32_16x16x32_bf16(
              af[rf], wf[cf], acc[rf][cf], 0, 0, 0);
    }
  }

  // C/D layout: col=lane&15, row=(lane>>4)*4+j  [m89 verified]
#pragma unroll
  for (int cf = 0; cf < NCF; ++cf) {
    int c = colbase + cf * 16 + (lane & 15);
    float bb0 = b0[c], bbe = be[c];
#pragma unroll
    for (int rf = 0; rf < 4; ++rf) {
#pragma unroll
      for (int j = 0; j < 4; ++j) {
        int lr = rf * 16 + (lane >> 4) * 4 + j;
        int r = row0 + lr;
        if (r < M) {
          float v = acc[rf][cf][j] + bb0 + degmask[lr] * bbe;
          if (LRELU) v = (v >= 0.f) ? v : 0.01f * v;
          if (OUTBF16)
            ((unsigned short*)outv)[(size_t)r * N + c] = f2bf(v);
          else
            ((float*)outv)[(size_t)r * N + c] = v;
        }
      }
    }
  }
}

extern "C" void kernel_launch(void* const* d_in, const int* in_sizes, int n_in,
                              void* d_out, int out_size, void* d_ws,
                              size_t ws_size, hipStream_t stream) {
  const float* emb_u = (const float*)d_in[0];
  const float* emb_i = (const float*)d_in[1];
  const float* W1_0  = (const float*)d_in[2];
  const float* b1_0  = (const float*)d_in[3];
  const float* W1_ui = (const float*)d_in[4];
  const float* b1_ui = (const float*)d_in[5];
  const float* W1_iu = (const float*)d_in[6];
  const float* b1_iu = (const float*)d_in[7];
  const float* W2_0  = (const float*)d_in[8];
  const float* b2_0  = (const float*)d_in[9];
  const float* W2_ui = (const float*)d_in[10];
  const float* b2_ui = (const float*)d_in[11];
  const float* W2_iu = (const float*)d_in[12];
  const float* b2_iu = (const float*)d_in[13];
  const int* src_ui = (const int*)d_in[14];
  const int* dst_ui = (const int*)d_in[15];
  const int* src_iu = (const int*)d_in[16];
  const int* dst_iu = (const int*)d_in[17];
  float* out = (float*)d_out;

  // ---- workspace layout (~130 MB) ----
  char* p = (char*)d_ws;
  unsigned short* WT1i = (unsigned short*)p; p += 65536;
  unsigned short* WT1u = (unsigned short*)p; p += 65536;
  unsigned short* WT2i = (unsigned short*)p; p += 32768;
  unsigned short* WT2u = (unsigned short*)p; p += 32768;
  int* cur_i = (int*)p; p += 400128;                 // degrees item-side
  int* cur_u = (int*)p; p += 400128;                 // degrees user-side
  int* csr_ui = (int*)p; p += (size_t)100032 * DEGCAP * 4;  // 12.8 MB
  int* csr_iu = (int*)p; p += (size_t)100032 * DEGCAP * 4;
  const size_t FB = (size_t)N_USER * 128 * 2;        // 25.6 MB
  unsigned short* ebu  = (unsigned short*)p; p += FB;  // -> hu (in place)
  unsigned short* ebi  = (unsigned short*)p; p += FB;  // -> hi (in place)
  unsigned short* aggA = (unsigned short*)p; p += FB;
  unsigned short* aggB = (unsigned short*)p; p += FB;
  unsigned short* hu = ebu;
  unsigned short* hi = ebi;

  const int GG = (N_USER + 63) / 64;  // 1563

  hipMemsetAsync(cur_i, 0, 2 * 400128, stream);
  setup_k<<<16792, 256, 0, stream>>>(src_ui, dst_ui, cur_i, csr_ui,
                                     src_iu, dst_iu, cur_u, csr_iu,
                                     emb_u, emb_i, ebu, ebi,
                                     W1_0, W1_ui, W1_iu, W2_0, W2_ui, W2_iu,
                                     WT1i, WT1u, WT2i, WT2u);

  // ---- layer 1: gather-mean (both dirs), fused double-GEMM + lrelu ----
  agg2_k<<<2 * 6250, 256, 0, stream>>>(
      ebu, cur_i, csr_ui, aggA, ebi, cur_u, csr_iu, aggB, 6250);
  gemm2_k<128, true, true><<<2 * GG, 256, 0, stream>>>(
      ebi, aggA, WT1i, b1_0, b1_ui, cur_i, hi,
      ebu, aggB, WT1u, b1_0, b1_iu, cur_u, hu, N_USER, GG);

  // ---- layer 2: gather-mean (both dirs), fused double-GEMM -> fp32 out ----
  agg2_k<<<2 * 6250, 256, 0, stream>>>(
      hu, cur_i, csr_ui, aggA, hi, cur_u, csr_iu, aggB, 6250);
  gemm2_k<64, false, false><<<2 * GG, 256, 0, stream>>>(
      hi, aggA, WT2i, b2_0, b2_ui, cur_i, out + (size_t)N_USER * 64,
      hu, aggB, WT2u, b2_0, b2_iu, cur_u, out, N_USER, GG);
}